// Round 1
// baseline (404.419 us; speedup 1.0000x reference)
//
#include <hip/hip_runtime.h>

#define IMG_H 2048
#define IMG_W 2048
#define IMG_C 8

__global__ __launch_bounds__(256) void idx2pixel_kernel(
    const float2* __restrict__ coords,
    const float* __restrict__ visible,
    const float* __restrict__ bias,
    float* __restrict__ out,
    int n)
{
    int idx = blockIdx.x * blockDim.x + threadIdx.x;
    if (idx >= n) return;

    float2 cv = coords[idx];
    float b0 = bias[0];
    float b1 = bias[1];

    // idx = coords - bias; c = max(idx, 0); low = min(floor(c), H-2); delta = c - low
    float c0 = fmaxf(cv.x - b0, 0.0f);
    float c1 = fmaxf(cv.y - b1, 0.0f);
    float low0 = fminf(floorf(c0), (float)(IMG_H - 2));
    float low1 = fminf(floorf(c1), (float)(IMG_W - 2));
    float d0 = c0 - low0;
    float d1 = c1 - low1;
    int i0 = (int)low0;
    int i1 = (int)low1;

    // visible[i0, i1, :] and visible[i0, i1+1, :] are contiguous 64 B, float4-aligned.
    const float* row_t = visible + ((size_t)i0 * IMG_W + (size_t)i1) * IMG_C;       // tl | bl
    const float* row_b = row_t + (size_t)IMG_W * IMG_C;                              // tr | br

    float4 tl_a = *(const float4*)(row_t + 0);
    float4 tl_b = *(const float4*)(row_t + 4);
    float4 bl_a = *(const float4*)(row_t + 8);
    float4 bl_b = *(const float4*)(row_t + 12);
    float4 tr_a = *(const float4*)(row_b + 0);
    float4 tr_b = *(const float4*)(row_b + 4);
    float4 br_a = *(const float4*)(row_b + 8);
    float4 br_b = *(const float4*)(row_b + 12);

    // mid_bottom = br + d0*(bl-br); mid_top = tr + d0*(tl-tr);
    // out = mid_bottom + d1*(mid_top - mid_bottom)
    float4 o_a, o_b;
    {
        float mb, mt;
        mb = br_a.x + d0 * (bl_a.x - br_a.x); mt = tr_a.x + d0 * (tl_a.x - tr_a.x);
        o_a.x = mb + d1 * (mt - mb);
        mb = br_a.y + d0 * (bl_a.y - br_a.y); mt = tr_a.y + d0 * (tl_a.y - tr_a.y);
        o_a.y = mb + d1 * (mt - mb);
        mb = br_a.z + d0 * (bl_a.z - br_a.z); mt = tr_a.z + d0 * (tl_a.z - tr_a.z);
        o_a.z = mb + d1 * (mt - mb);
        mb = br_a.w + d0 * (bl_a.w - br_a.w); mt = tr_a.w + d0 * (tl_a.w - tr_a.w);
        o_a.w = mb + d1 * (mt - mb);

        mb = br_b.x + d0 * (bl_b.x - br_b.x); mt = tr_b.x + d0 * (tl_b.x - tr_b.x);
        o_b.x = mb + d1 * (mt - mb);
        mb = br_b.y + d0 * (bl_b.y - br_b.y); mt = tr_b.y + d0 * (tl_b.y - tr_b.y);
        o_b.y = mb + d1 * (mt - mb);
        mb = br_b.z + d0 * (bl_b.z - br_b.z); mt = tr_b.z + d0 * (tl_b.z - tr_b.z);
        o_b.z = mb + d1 * (mt - mb);
        mb = br_b.w + d0 * (bl_b.w - br_b.w); mt = tr_b.w + d0 * (tl_b.w - tr_b.w);
        o_b.w = mb + d1 * (mt - mb);
    }

    float4* outp = (float4*)(out + (size_t)idx * IMG_C);
    outp[0] = o_a;
    outp[1] = o_b;
}

extern "C" void kernel_launch(void* const* d_in, const int* in_sizes, int n_in,
                              void* d_out, int out_size, void* d_ws, size_t ws_size,
                              hipStream_t stream) {
    const float2* coords  = (const float2*)d_in[0];   // (N, 2) f32
    const float*  visible = (const float*)d_in[1];    // (H, W, C) f32
    const float*  bias    = (const float*)d_in[2];    // (2,) f32
    float* out = (float*)d_out;                       // (N, C) f32

    int n = in_sizes[0] / 2;  // N samples
    int block = 256;
    int grid = (n + block - 1) / block;
    idx2pixel_kernel<<<grid, block, 0, stream>>>(coords, visible, bias, out, n);
}

// Round 2
// 398.649 us; speedup vs baseline: 1.0145x; 1.0145x over previous
//
#include <hip/hip_runtime.h>

#define IMG_H 2048
#define IMG_W 2048
#define IMG_C 8

// Two lanes per sample: lane `part` handles channels [4*part, 4*part+4).
// Adjacent lanes load contiguous 32 B per gather instruction -> coalesced
// into one request per lane-pair, halving request count vs 1-thread/sample.
__global__ __launch_bounds__(256) void idx2pixel_kernel(
    const float2* __restrict__ coords,
    const float* __restrict__ visible,
    const float* __restrict__ bias,
    float* __restrict__ out,
    int n)
{
    int tid = blockIdx.x * blockDim.x + threadIdx.x;
    int s    = tid >> 1;
    int part = tid & 1;
    if (s >= n) return;

    float2 cv = coords[s];
    float b0 = bias[0];
    float b1 = bias[1];

    // idx = coords - bias; c = max(idx, 0); low = min(floor(c), H-2); delta = c - low
    float c0 = fmaxf(cv.x - b0, 0.0f);
    float c1 = fmaxf(cv.y - b1, 0.0f);
    float low0 = fminf(floorf(c0), (float)(IMG_H - 2));
    float low1 = fminf(floorf(c1), (float)(IMG_W - 2));
    float d0 = c0 - low0;
    float d1 = c1 - low1;
    int i0 = (int)low0;
    int i1 = (int)low1;

    // Pixel (i0,i1) quad `part`; +8 floats = pixel (i0,i1+1) same quad.
    const float* p_t = visible + ((size_t)i0 * IMG_W + (size_t)i1) * IMG_C + part * 4;
    const float* p_b = p_t + (size_t)IMG_W * IMG_C;

    float4 tl = *(const float4*)(p_t);       // visible[i0,   i1,   4p:4p+4]
    float4 bl = *(const float4*)(p_t + 8);   // visible[i0,   i1+1, 4p:4p+4]
    float4 tr = *(const float4*)(p_b);       // visible[i0+1, i1,   4p:4p+4]
    float4 br = *(const float4*)(p_b + 8);   // visible[i0+1, i1+1, 4p:4p+4]

    // mid_bottom = br + d0*(bl-br); mid_top = tr + d0*(tl-tr);
    // out = mid_bottom + d1*(mid_top - mid_bottom)   (same order as reference)
    float4 o;
    {
        float mb, mt;
        mb = br.x + d0 * (bl.x - br.x); mt = tr.x + d0 * (tl.x - tr.x);
        o.x = mb + d1 * (mt - mb);
        mb = br.y + d0 * (bl.y - br.y); mt = tr.y + d0 * (tl.y - tr.y);
        o.y = mb + d1 * (mt - mb);
        mb = br.z + d0 * (bl.z - br.z); mt = tr.z + d0 * (tl.z - tr.z);
        o.z = mb + d1 * (mt - mb);
        mb = br.w + d0 * (bl.w - br.w); mt = tr.w + d0 * (tl.w - tr.w);
        o.w = mb + d1 * (mt - mb);
    }

    *(float4*)(out + (size_t)s * IMG_C + part * 4) = o;
}

extern "C" void kernel_launch(void* const* d_in, const int* in_sizes, int n_in,
                              void* d_out, int out_size, void* d_ws, size_t ws_size,
                              hipStream_t stream) {
    const float2* coords  = (const float2*)d_in[0];   // (N, 2) f32
    const float*  visible = (const float*)d_in[1];    // (H, W, C) f32
    const float*  bias    = (const float*)d_in[2];    // (2,) f32
    float* out = (float*)d_out;                       // (N, C) f32

    int n = in_sizes[0] / 2;          // N samples
    long long threads = 2LL * n;      // 2 lanes per sample
    int block = 256;
    long long grid = (threads + block - 1) / block;
    idx2pixel_kernel<<<(int)grid, block, 0, stream>>>(coords, visible, bias, out, n);
}